// Round 16
// baseline (103.637 us; speedup 1.0000x reference)
//
#include <hip/hip_runtime.h>

#define IDX_BASE 16777216UL   // 4096*64*64
#define LOSS_IDX 17039360UL   // IDX_BASE + 4096*64
#define EPS2 0.02f            // rescue window; covers f16x3 + key-mask err (R14/R15-validated)

typedef float4 f4;
typedef _Float16 half8 __attribute__((ext_vector_type(8)));
typedef float f32x4 __attribute__((ext_vector_type(4)));

static __device__ __forceinline__ unsigned umax(unsigned a, unsigned b) { return a > b ? a : b; }
static __device__ __forceinline__ unsigned umin(unsigned a, unsigned b) { return a < b ? a : b; }
// monotone float<->u32 (R14/R15-validated)
static __device__ __forceinline__ unsigned f2mono(float s) {
    unsigned u = __float_as_uint(s);
    return u ^ (unsigned)(((int)u >> 31) | 0x80000000);
}
static __device__ __forceinline__ float mono2f(unsigned v) {
    return __uint_as_float(v ^ (((unsigned)((int)(~v) >> 31)) | 0x80000000u));
}

// ---- precompute code A-fragments (f16 hi/lo) + fused c2 (R14/R15-validated) ----
__global__ __launch_bounds__(256) void pq_frag(const float* __restrict__ cb,
                                               half8* __restrict__ fragbuf,
                                               float* __restrict__ c2) {
    int bx = blockIdx.x, tid = threadIdx.x;
    int m = bx >> 2, sub = bx & 3;
    int w = tid >> 6, lane = tid & 63, lh = lane >> 4, l15 = lane & 15;
    const float* cbm = cb + (size_t)m * (256 * 64);
    half8* fbm = fragbuf + (size_t)m * (16 * 4 * 64);
    int tile = w * 4 + sub;
    int code = tile * 16 + l15;
    const float* crow = cbm + code * 64 + lh * 8;
    float ss = 0.f;
    #pragma unroll
    for (int s = 0; s < 2; ++s) {
        f4 a = *reinterpret_cast<const f4*>(crow + s * 32);
        f4 b = *reinterpret_cast<const f4*>(crow + s * 32 + 4);
        float v[8] = {a.x, a.y, a.z, a.w, b.x, b.y, b.z, b.w};
        half8 hi, lo;
        #pragma unroll
        for (int e = 0; e < 8; ++e) {
            _Float16 h = (_Float16)v[e];
            hi[e] = h; lo[e] = (_Float16)(v[e] - (float)h);
            ss = fmaf(v[e], v[e], ss);
        }
        fbm[(tile * 4 + s * 2 + 0) * 64 + lane] = hi;
        fbm[(tile * 4 + s * 2 + 1) * 64 + lane] = lo;
    }
    ss += __shfl_xor(ss, 16, 64);
    ss += __shfl_xor(ss, 32, 64);
    if (lh == 0) c2[m * 256 + code] = ss;
}

// ---- main: 64-thread blocks, wave-autonomous. NO LDS, NO barriers.
//      Wave = 64 rows x 256 codes; z f16-frags resident; frags streamed. ----
__global__ __launch_bounds__(64, 4) void pq_main(
    const float* __restrict__ z, const float* __restrict__ cb,
    const float* __restrict__ c2ws, const half8* __restrict__ fragbuf,
    float* __restrict__ out, float* __restrict__ partial)
{
    const int bx = blockIdx.x, lane = threadIdx.x;
    const int m = ((bx & 7) << 3) | ((bx >> 3) & 7);   // XCD m-octet (R11/R15-proven)
    const int chunk = bx >> 6;                          // 0..63
    const int rowbase = chunk * 64;
    const int lh = lane >> 4, l15 = lane & 15;

    const float* __restrict__ cbm = cb + (size_t)m * (256 * 64);
    const f4* cb4m = reinterpret_cast<const f4*>(cbm);
    const half8* __restrict__ fb = fragbuf + (size_t)m * (16 * 4 * 64);
    const f4* __restrict__ c2t = reinterpret_cast<const f4*>(c2ws + m * 256);

    // ---- resident z B-fragments, 4 row-tiles (R10-validated conversion) ----
    half8 zh[4][2], zl[4][2];
    #pragma unroll
    for (int rt = 0; rt < 4; ++rt) {
        size_t rh = (size_t)(rowbase + rt * 16 + l15);
        const float* zb = z + (rh * 64 + m) * 64 + lh * 8;
        f4 p0 = *reinterpret_cast<const f4*>(zb);
        f4 p1 = *reinterpret_cast<const f4*>(zb + 4);
        f4 p2 = *reinterpret_cast<const f4*>(zb + 32);
        f4 p3 = *reinterpret_cast<const f4*>(zb + 36);
        float v0[8] = {p0.x,p0.y,p0.z,p0.w,p1.x,p1.y,p1.z,p1.w};
        float v1[8] = {p2.x,p2.y,p2.z,p2.w,p3.x,p3.y,p3.z,p3.w};
        #pragma unroll
        for (int e = 0; e < 8; ++e) {
            _Float16 a = (_Float16)v0[e];
            zh[rt][0][e] = a; zl[rt][0][e] = (_Float16)(v0[e] - (float)a);
            _Float16 b = (_Float16)v1[e];
            zh[rt][1][e] = b; zl[rt][1][e] = (_Float16)(v1[e] - (float)b);
        }
    }

    unsigned K1[4] = {0u,0u,0u,0u}, K2[4] = {0u,0u,0u,0u};

    // ---- 16 code-tiles: 4 frag loads + c2 + 4x6 MFMA + packed tree top-2 ----
    #pragma unroll 4
    for (int tile = 0; tile < 16; ++tile) {
        half8 ah0 = fb[(tile * 4 + 0) * 64 + lane];
        half8 al0 = fb[(tile * 4 + 1) * 64 + lane];
        half8 ah1 = fb[(tile * 4 + 2) * 64 + lane];
        half8 al1 = fb[(tile * 4 + 3) * 64 + lane];
        f4 cv = c2t[tile * 4 + lh];
        f32x4 ci; ci[0] = -0.5f*cv.x; ci[1] = -0.5f*cv.y; ci[2] = -0.5f*cv.z; ci[3] = -0.5f*cv.w;
        const unsigned pb = 255u - (unsigned)(tile * 16 + lh * 4);
        #pragma unroll
        for (int rt = 0; rt < 4; ++rt) {
            f32x4 acc = ci;
            acc = __builtin_amdgcn_mfma_f32_16x16x32_f16(ah0, zh[rt][0], acc, 0, 0, 0);
            acc = __builtin_amdgcn_mfma_f32_16x16x32_f16(ah1, zh[rt][1], acc, 0, 0, 0);
            acc = __builtin_amdgcn_mfma_f32_16x16x32_f16(ah0, zl[rt][0], acc, 0, 0, 0);
            acc = __builtin_amdgcn_mfma_f32_16x16x32_f16(ah1, zl[rt][1], acc, 0, 0, 0);
            acc = __builtin_amdgcn_mfma_f32_16x16x32_f16(al0, zh[rt][0], acc, 0, 0, 0);
            acc = __builtin_amdgcn_mfma_f32_16x16x32_f16(al1, zh[rt][1], acc, 0, 0, 0);
            unsigned kk0 = (f2mono(acc[0]) & 0xFFFFFF00u) | (pb - 0u);
            unsigned kk1 = (f2mono(acc[1]) & 0xFFFFFF00u) | (pb - 1u);
            unsigned kk2 = (f2mono(acc[2]) & 0xFFFFFF00u) | (pb - 2u);
            unsigned kk3 = (f2mono(acc[3]) & 0xFFFFFF00u) | (pb - 3u);
            unsigned a  = umax(kk0, kk1), b2 = umin(kk0, kk1);
            unsigned c  = umax(kk2, kk3), d  = umin(kk2, kk3);
            unsigned t1 = umax(a, c);
            unsigned t2 = umax(umin(a, c), umax(b2, d));
            K2[rt] = umax(umax(K2[rt], t2), umin(K1[rt], t1));
            K1[rt] = umax(K1[rt], t1);
        }
    }

    // ---- per row-tile: lane-group merge, rescue (rare), epilogue (R10-validated) ----
    float lsum = 0.f;
    #pragma unroll
    for (int rt = 0; rt < 4; ++rt) {
        #pragma unroll
        for (int off = 16; off <= 32; off <<= 1) {
            unsigned o1 = (unsigned)__shfl_xor((int)K1[rt], off, 64);
            unsigned o2 = (unsigned)__shfl_xor((int)K2[rt], off, 64);
            K2[rt] = umax(umax(K2[rt], o2), umin(K1[rt], o1));
            K1[rt] = umax(K1[rt], o1);
        }
        int cd = 255 - (int)(K1[rt] & 0xFFu);
        float s1 = mono2f(K1[rt] & 0xFFFFFF00u);
        float s2 = mono2f(K2[rt] & 0xFFFFFF00u);
        bool need = (s1 - s2) < EPS2;
        unsigned mask = (unsigned)(__ballot(need)) & 0xFFFFu;
        while (mask) {                       // rescue: exact fp32 (validated R4/R10 math)
            int row = __builtin_ctz(mask); mask &= mask - 1;
            size_t rg = (size_t)(rowbase + rt * 16 + row);
            const f4* zr4 = reinterpret_cast<const f4*>(z + (rg * 64 + m) * 64);
            float bs = -1e30f; int bkx = 0;
            #pragma unroll 1
            for (int j = 0; j < 4; ++j) {
                int k = j * 64 + lane;
                float s = -0.5f * c2ws[m * 256 + k];
                #pragma unroll
                for (int d4 = 0; d4 < 16; ++d4) {
                    f4 cc = cb4m[k * 16 + d4];
                    f4 zz = zr4[d4];
                    s = fmaf(zz.x, cc.x, s); s = fmaf(zz.y, cc.y, s);
                    s = fmaf(zz.z, cc.z, s); s = fmaf(zz.w, cc.w, s);
                }
                if (s > bs) { bs = s; bkx = k; }
            }
            #pragma unroll
            for (int off = 1; off < 64; off <<= 1) {
                float ov = __shfl_xor(bs, off, 64);
                int   ok = __shfl_xor(bkx, off, 64);
                if (ov > bs || (ov == bs && ok < bkx)) { bs = ov; bkx = ok; }
            }
            if (l15 == row) cd = bkx;
        }
        // epilogue: exact codebook copy + loss via hi+lo reconstruction (R10-validated)
        {
            size_t rg = (size_t)(rowbase + rt * 16 + l15);
            const f4* qb = cb4m + (size_t)cd * 16 + lh * 2;
            f4 q0 = qb[0], q1 = qb[1], q2 = qb[8], q3 = qb[9];
            float* ob = out + (rg * 64 + m) * 64 + lh * 8;
            *reinterpret_cast<f4*>(ob)      = q0;
            *reinterpret_cast<f4*>(ob + 4)  = q1;
            *reinterpret_cast<f4*>(ob + 32) = q2;
            *reinterpret_cast<f4*>(ob + 36) = q3;
            float qq0[8] = {q0.x,q0.y,q0.z,q0.w,q1.x,q1.y,q1.z,q1.w};
            float qq1[8] = {q2.x,q2.y,q2.z,q2.w,q3.x,q3.y,q3.z,q3.w};
            #pragma unroll
            for (int e = 0; e < 8; ++e) {
                float zr0 = (float)zh[rt][0][e] + (float)zl[rt][0][e];
                float zr1 = (float)zh[rt][1][e] + (float)zl[rt][1][e];
                float d0 = qq0[e] - zr0, d1 = qq1[e] - zr1;
                lsum = fmaf(d0, d0, lsum); lsum = fmaf(d1, d1, lsum);
            }
            if (lane < 16)
                out[IDX_BASE + (size_t)(rowbase + rt * 16 + lane) * 64 + m] = (float)cd;
        }
    }

    // ---- per-wave loss partial (no barrier, no LDS) ----
    #pragma unroll
    for (int off = 1; off < 64; off <<= 1) lsum += __shfl_xor(lsum, off, 64);
    if (lane == 0) partial[bx] = lsum;
}

// ---- deterministic final reduction of 4096 wave partials -> q_loss ----
__global__ __launch_bounds__(256) void pq_loss(const float* __restrict__ partial,
                                               float* __restrict__ out)
{
    __shared__ float sW[4];
    float s = 0.f;
    #pragma unroll
    for (int i = 0; i < 16; ++i) s += partial[threadIdx.x + i * 256];
    #pragma unroll
    for (int off = 1; off < 64; off <<= 1) s += __shfl_xor(s, off, 64);
    if ((threadIdx.x & 63) == 0) sW[threadIdx.x >> 6] = s;
    __syncthreads();
    if (threadIdx.x == 0)
        out[LOSS_IDX] = ((sW[0] + sW[1]) + (sW[2] + sW[3])) * (1.25f / 16777216.0f);
}

extern "C" void kernel_launch(void* const* d_in, const int* in_sizes, int n_in,
                              void* d_out, int out_size, void* d_ws, size_t ws_size,
                              hipStream_t stream) {
    const float* zp  = (const float*)d_in[0];
    const float* cbp = (const float*)d_in[1];
    float* outp = (float*)d_out;
    float* c2ws = (float*)d_ws;                        // 16384 floats (64 KB)
    half8* frag = (half8*)((float*)d_ws + 16384);      // 4 MB
    float* part = (float*)d_ws + 16384 + 1048576;      // 4096 floats

    pq_frag<<<dim3(256),  dim3(256), 0, stream>>>(cbp, frag, c2ws);
    pq_main<<<dim3(4096), dim3(64),  0, stream>>>(zp, cbp, c2ws, frag, outp, part);
    pq_loss<<<dim3(1),    dim3(256), 0, stream>>>(part, outp);
}

// Round 17
// 94.009 us; speedup vs baseline: 1.1024x; 1.1024x over previous
//
#include <hip/hip_runtime.h>

#define IDX_BASE 16777216UL   // 4096*64*64
#define LOSS_IDX 17039360UL   // IDX_BASE + 4096*64
#define EPS2 0.02f            // rescue window; covers f16x3 + key-mask err (R14/R15-validated)

typedef float4 f4;
typedef _Float16 half8 __attribute__((ext_vector_type(8)));
typedef float f32x4 __attribute__((ext_vector_type(4)));

static __device__ __forceinline__ unsigned umax(unsigned a, unsigned b) { return a > b ? a : b; }
static __device__ __forceinline__ unsigned umin(unsigned a, unsigned b) { return a < b ? a : b; }
// monotone float<->u32 (R14/R15-validated)
static __device__ __forceinline__ unsigned f2mono(float s) {
    unsigned u = __float_as_uint(s);
    return u ^ (unsigned)(((int)u >> 31) | 0x80000000);
}
static __device__ __forceinline__ float mono2f(unsigned v) {
    return __uint_as_float(v ^ (((unsigned)((int)(~v) >> 31)) | 0x80000000u));
}

// ---- precompute code A-fragments (f16 hi/lo) + fused c2 (R14/R15-validated) ----
__global__ __launch_bounds__(256) void pq_frag(const float* __restrict__ cb,
                                               half8* __restrict__ fragbuf,
                                               float* __restrict__ c2) {
    int bx = blockIdx.x, tid = threadIdx.x;
    int m = bx >> 2, sub = bx & 3;
    int w = tid >> 6, lane = tid & 63, lh = lane >> 4, l15 = lane & 15;
    const float* cbm = cb + (size_t)m * (256 * 64);
    half8* fbm = fragbuf + (size_t)m * (16 * 4 * 64);
    int tile = w * 4 + sub;
    int code = tile * 16 + l15;
    const float* crow = cbm + code * 64 + lh * 8;
    float ss = 0.f;
    #pragma unroll
    for (int s = 0; s < 2; ++s) {
        f4 a = *reinterpret_cast<const f4*>(crow + s * 32);
        f4 b = *reinterpret_cast<const f4*>(crow + s * 32 + 4);
        float v[8] = {a.x, a.y, a.z, a.w, b.x, b.y, b.z, b.w};
        half8 hi, lo;
        #pragma unroll
        for (int e = 0; e < 8; ++e) {
            _Float16 h = (_Float16)v[e];
            hi[e] = h; lo[e] = (_Float16)(v[e] - (float)h);
            ss = fmaf(v[e], v[e], ss);
        }
        fbm[(tile * 4 + s * 2 + 0) * 64 + lane] = hi;
        fbm[(tile * 4 + s * 2 + 1) * 64 + lane] = lo;
    }
    ss += __shfl_xor(ss, 16, 64);
    ss += __shfl_xor(ss, 32, 64);
    if (lh == 0) c2[m * 256 + code] = ss;
}

// Block = one m x 128 rows, 4 waves; wave w owns codes w*64..+63 (A-frags resident).
// z converted ONCE (per-wave 2 row-tiles) into LDS frag buffer; main loop B-operand
// is pure ds_read_b128 -> MFMA (no VALU on the critical path).
__global__ __launch_bounds__(256, 3) void pq_main(
    const float* __restrict__ z, const float* __restrict__ cb,
    const float* __restrict__ c2ws, const half8* __restrict__ fragbuf,
    float* __restrict__ out, float* __restrict__ partial)
{
    __shared__ half8    sZfrag[8 * 4 * 64];   // 32 KB: [(rt*4+u)*64 + lane]
    __shared__ unsigned sK1[4 * 128];
    __shared__ unsigned sK2[4 * 128];
    __shared__ int      sBest[128];
    __shared__ float    sW[4];

    const int tid = threadIdx.x, bx = blockIdx.x;
    const int m = ((bx & 7) << 3) | ((bx >> 3) & 7);   // XCD m-octet (R11/R15-proven)
    const int chunk = bx >> 6;                          // 0..31
    const int w = tid >> 6, lane = tid & 63;
    const int lh = lane >> 4, l15 = lane & 15;
    const unsigned payBase = 255u - (unsigned)(w * 64 + lh * 4);  // payload = 255 - code

    const float* __restrict__ cbm = cb + (size_t)m * (256 * 64);
    const f4* cb4m = reinterpret_cast<const f4*>(cbm);

    // ---- convert phase: wave w converts row-tiles 2w, 2w+1 (R10-validated math) ----
    #pragma unroll
    for (int i = 0; i < 2; ++i) {
        int rt = w * 2 + i;
        size_t rh = (size_t)(chunk * 128 + rt * 16 + l15);
        const float* zb = z + (rh * 64 + m) * 64 + lh * 8;
        f4 p0 = *reinterpret_cast<const f4*>(zb);
        f4 p1 = *reinterpret_cast<const f4*>(zb + 4);
        f4 p2 = *reinterpret_cast<const f4*>(zb + 32);
        f4 p3 = *reinterpret_cast<const f4*>(zb + 36);
        float v0[8] = {p0.x,p0.y,p0.z,p0.w,p1.x,p1.y,p1.z,p1.w};
        float v1[8] = {p2.x,p2.y,p2.z,p2.w,p3.x,p3.y,p3.z,p3.w};
        half8 h0, l0, h1, l1;
        #pragma unroll
        for (int e = 0; e < 8; ++e) {
            _Float16 a = (_Float16)v0[e];
            h0[e] = a; l0[e] = (_Float16)(v0[e] - (float)a);
            _Float16 b = (_Float16)v1[e];
            h1[e] = b; l1[e] = (_Float16)(v1[e] - (float)b);
        }
        sZfrag[rt * 256 +   0 + lane] = h0;
        sZfrag[rt * 256 +  64 + lane] = l0;
        sZfrag[rt * 256 + 128 + lane] = h1;
        sZfrag[rt * 256 + 192 + lane] = l1;
    }

    // ---- A-fragments: 16 coalesced loads from fragbuf [R11/R15] ----
    const half8* __restrict__ fb = fragbuf + (size_t)m * (16 * 4 * 64);
    half8 ah[4][2], al[4][2];
    #pragma unroll
    for (int t = 0; t < 4; ++t) {
        #pragma unroll
        for (int s = 0; s < 2; ++s) {
            ah[t][s] = fb[((w * 4 + t) * 4 + s * 2 + 0) * 64 + lane];
            al[t][s] = fb[((w * 4 + t) * 4 + s * 2 + 1) * 64 + lane];
        }
    }
    // ---- c2 init per lane: k = w*64 + t*16 + lh*4 + r [R15] ----
    const f4* __restrict__ c2t = reinterpret_cast<const f4*>(c2ws + m * 256);
    f32x4 c2i[4];
    #pragma unroll
    for (int t = 0; t < 4; ++t) {
        f4 cv = c2t[(w * 4 + t) * 4 + lh];
        c2i[t][0] = -0.5f*cv.x; c2i[t][1] = -0.5f*cv.y;
        c2i[t][2] = -0.5f*cv.z; c2i[t][3] = -0.5f*cv.w;
    }

    __syncthreads();   // sZfrag complete

    // ---- main: 8 row-tiles x {4 ds_read_b128 + 4x6 MFMA + packed top-2 [R15]} ----
    #pragma unroll 1
    for (int rt = 0; rt < 8; ++rt) {
        const half8* zf = &sZfrag[rt * 256 + lane];
        half8 bh0 = zf[0], bl0 = zf[64], bh1 = zf[128], bl1 = zf[192];
        unsigned K1 = 0u, K2 = 0u;
        #pragma unroll
        for (int t = 0; t < 4; ++t) {
            const unsigned pb = payBase - (unsigned)(t * 16);
            f32x4 acc = c2i[t];
            acc = __builtin_amdgcn_mfma_f32_16x16x32_f16(ah[t][0], bh0, acc, 0, 0, 0);
            acc = __builtin_amdgcn_mfma_f32_16x16x32_f16(ah[t][1], bh1, acc, 0, 0, 0);
            acc = __builtin_amdgcn_mfma_f32_16x16x32_f16(ah[t][0], bl0, acc, 0, 0, 0);
            acc = __builtin_amdgcn_mfma_f32_16x16x32_f16(ah[t][1], bl1, acc, 0, 0, 0);
            acc = __builtin_amdgcn_mfma_f32_16x16x32_f16(al[t][0], bh0, acc, 0, 0, 0);
            acc = __builtin_amdgcn_mfma_f32_16x16x32_f16(al[t][1], bh1, acc, 0, 0, 0);
            unsigned kk0 = (f2mono(acc[0]) & 0xFFFFFF00u) | (pb - 0u);
            unsigned kk1 = (f2mono(acc[1]) & 0xFFFFFF00u) | (pb - 1u);
            unsigned kk2 = (f2mono(acc[2]) & 0xFFFFFF00u) | (pb - 2u);
            unsigned kk3 = (f2mono(acc[3]) & 0xFFFFFF00u) | (pb - 3u);
            unsigned a  = umax(kk0, kk1), b2 = umin(kk0, kk1);
            unsigned c  = umax(kk2, kk3), d  = umin(kk2, kk3);
            unsigned t1 = umax(a, c);
            unsigned t2 = umax(umin(a, c), umax(b2, d));
            K2 = umax(umax(K2, t2), umin(K1, t1));
            K1 = umax(K1, t1);
        }
        #pragma unroll
        for (int off = 16; off <= 32; off <<= 1) {   // merge 4 lane-groups per row
            unsigned o1 = (unsigned)__shfl_xor((int)K1, off, 64);
            unsigned o2 = (unsigned)__shfl_xor((int)K2, off, 64);
            K2 = umax(umax(K2, o2), umin(K1, o1));
            K1 = umax(K1, o1);
        }
        if (lane < 16) {
            sK1[w * 128 + rt * 16 + lane] = K1;
            sK2[w * 128 + rt * 16 + lane] = K2;
        }
    }
    __syncthreads();

    // ---- per-row merge across 4 waves (packed umax tree) [R15] ----
    if (tid < 128) {
        unsigned G1 = 0u, G2 = 0u;
        #pragma unroll
        for (int w2 = 0; w2 < 4; ++w2) {
            unsigned k1w = sK1[w2 * 128 + tid];
            unsigned k2w = sK2[w2 * 128 + tid];
            G2 = umax(umax(G2, k2w), umin(G1, k1w));
            G1 = umax(G1, k1w);
        }
        float s1 = mono2f(G1 & 0xFFFFFF00u);
        float s2 = mono2f(G2 & 0xFFFFFF00u);
        sBest[tid] = (s1 - s2 < EPS2) ? -1 : (int)(255u - (G1 & 0xFFu));
    }
    __syncthreads();

    // ---- rescue (rare): exact fp32, z from global (R4/R10-validated math) ----
    for (int row = w; row < 128; row += 4) {
        if (sBest[row] >= 0) continue;            // wave-uniform
        size_t rg = (size_t)(chunk * 128 + row);
        const f4* zr4 = reinterpret_cast<const f4*>(z + (rg * 64 + m) * 64);
        float bs = -1e30f; int bk = 0;
        #pragma unroll 1
        for (int j = 0; j < 4; ++j) {
            int k = j * 64 + lane;
            float s = -0.5f * c2ws[m * 256 + k];
            #pragma unroll
            for (int d4 = 0; d4 < 16; ++d4) {
                f4 cvv = cb4m[k * 16 + d4];
                f4 zz  = zr4[d4];
                s = fmaf(zz.x, cvv.x, s); s = fmaf(zz.y, cvv.y, s);
                s = fmaf(zz.z, cvv.z, s); s = fmaf(zz.w, cvv.w, s);
            }
            if (s > bs) { bs = s; bk = k; }
        }
        #pragma unroll
        for (int off = 1; off < 64; off <<= 1) {
            float ov = __shfl_xor(bs, off, 64);
            int   ok = __shfl_xor(bk, off, 64);
            if (ov > bs || (ov == bs && ok < bk)) { bs = ov; bk = ok; }
        }
        if (lane == 0) sBest[row] = bk;
    }
    __syncthreads();

    // ---- outputs: clean per-lane 128 B stores; z re-read from global (L2-hot) ----
    float lsum = 0.f;
    {
        int row = tid >> 1, hf = tid & 1;
        int k = sBest[row];
        size_t b = (size_t)(chunk * 128 + row);
        const f4* q4 = cb4m + (size_t)k * 16 + hf * 8;
        const f4* z4 = reinterpret_cast<const f4*>(z + (b * 64 + m) * 64) + hf * 8;
        f4*       o4 = reinterpret_cast<f4*>(out + (b * 64 + m) * 64) + hf * 8;
        float l0 = 0.f, l1 = 0.f;
        #pragma unroll
        for (int c = 0; c < 8; ++c) {
            f4 qv = q4[c], zv = z4[c];       // exact codebook copy, exact fp32 z
            o4[c] = qv;
            float d0 = qv.x - zv.x, d1 = qv.y - zv.y, d2 = qv.z - zv.z, d3 = qv.w - zv.w;
            l0 = fmaf(d0, d0, l0); l1 = fmaf(d1, d1, l1);
            l0 = fmaf(d2, d2, l0); l1 = fmaf(d3, d3, l1);
        }
        lsum = l0 + l1;
    }
    if (tid < 128)
        out[IDX_BASE + (size_t)(chunk * 128 + tid) * 64 + m] = (float)sBest[tid];
    #pragma unroll
    for (int off = 1; off < 64; off <<= 1) lsum += __shfl_xor(lsum, off, 64);
    if (lane == 0) sW[w] = lsum;
    __syncthreads();
    if (tid == 0) partial[bx] = (sW[0] + sW[1]) + (sW[2] + sW[3]);
}

// ---- deterministic final reduction of 2048 block partials -> q_loss ----
__global__ __launch_bounds__(256) void pq_loss(const float* __restrict__ partial,
                                               float* __restrict__ out)
{
    __shared__ float sW[4];
    float s = 0.f;
    #pragma unroll
    for (int i = 0; i < 8; ++i) s += partial[threadIdx.x + i * 256];
    #pragma unroll
    for (int off = 1; off < 64; off <<= 1) s += __shfl_xor(s, off, 64);
    if ((threadIdx.x & 63) == 0) sW[threadIdx.x >> 6] = s;
    __syncthreads();
    if (threadIdx.x == 0)
        out[LOSS_IDX] = ((sW[0] + sW[1]) + (sW[2] + sW[3])) * (1.25f / 16777216.0f);
}

extern "C" void kernel_launch(void* const* d_in, const int* in_sizes, int n_in,
                              void* d_out, int out_size, void* d_ws, size_t ws_size,
                              hipStream_t stream) {
    const float* zp  = (const float*)d_in[0];
    const float* cbp = (const float*)d_in[1];
    float* outp = (float*)d_out;
    float* c2ws = (float*)d_ws;                        // 16384 floats (64 KB)
    half8* frag = (half8*)((float*)d_ws + 16384);      // 4 MB
    float* part = (float*)d_ws + 16384 + 1048576;      // 2048 floats

    pq_frag<<<dim3(256),  dim3(256), 0, stream>>>(cbp, frag, c2ws);
    pq_main<<<dim3(2048), dim3(256), 0, stream>>>(zp, cbp, c2ws, frag, outp, part);
    pq_loss<<<dim3(1),    dim3(256), 0, stream>>>(part, outp);
}

// Round 18
// 82.526 us; speedup vs baseline: 1.2558x; 1.1391x over previous
//
#include <hip/hip_runtime.h>

#define IDX_BASE 16777216UL   // 4096*64*64
#define LOSS_IDX 17039360UL   // IDX_BASE + 4096*64
#define EPS2 0.02f            // rescue window; covers f16x3 + key-mask err (R14/R15-validated)

typedef float4 f4;
typedef _Float16 half8 __attribute__((ext_vector_type(8)));
typedef float f32x4 __attribute__((ext_vector_type(4)));

static __device__ __forceinline__ unsigned umax(unsigned a, unsigned b) { return a > b ? a : b; }
static __device__ __forceinline__ unsigned umin(unsigned a, unsigned b) { return a < b ? a : b; }
// monotone float<->u32 (R14/R15-validated)
static __device__ __forceinline__ unsigned f2mono(float s) {
    unsigned u = __float_as_uint(s);
    return u ^ (unsigned)(((int)u >> 31) | 0x80000000);
}
static __device__ __forceinline__ float mono2f(unsigned v) {
    return __uint_as_float(v ^ (((unsigned)((int)(~v) >> 31)) | 0x80000000u));
}

// ---- precompute code A-fragments (f16 hi/lo) + fused c2 (R14/R15-validated) ----
__global__ __launch_bounds__(256) void pq_frag(const float* __restrict__ cb,
                                               half8* __restrict__ fragbuf,
                                               float* __restrict__ c2) {
    int bx = blockIdx.x, tid = threadIdx.x;
    int m = bx >> 2, sub = bx & 3;
    int w = tid >> 6, lane = tid & 63, lh = lane >> 4, l15 = lane & 15;
    const float* cbm = cb + (size_t)m * (256 * 64);
    half8* fbm = fragbuf + (size_t)m * (16 * 4 * 64);
    int tile = w * 4 + sub;
    int code = tile * 16 + l15;
    const float* crow = cbm + code * 64 + lh * 8;
    float ss = 0.f;
    #pragma unroll
    for (int s = 0; s < 2; ++s) {
        f4 a = *reinterpret_cast<const f4*>(crow + s * 32);
        f4 b = *reinterpret_cast<const f4*>(crow + s * 32 + 4);
        float v[8] = {a.x, a.y, a.z, a.w, b.x, b.y, b.z, b.w};
        half8 hi, lo;
        #pragma unroll
        for (int e = 0; e < 8; ++e) {
            _Float16 h = (_Float16)v[e];
            hi[e] = h; lo[e] = (_Float16)(v[e] - (float)h);
            ss = fmaf(v[e], v[e], ss);
        }
        fbm[(tile * 4 + s * 2 + 0) * 64 + lane] = hi;
        fbm[(tile * 4 + s * 2 + 1) * 64 + lane] = lo;
    }
    ss += __shfl_xor(ss, 16, 64);
    ss += __shfl_xor(ss, 32, 64);
    if (lh == 0) c2[m * 256 + code] = ss;
}

// Block = one m x 128 rows, 512 threads / 8 waves; wave w owns codes w*32..+31
// (A-frags 32 regs). z converted ONCE into LDS frag buffer (wave w -> row-tile w);
// inner loop is pure ds_read_b128 -> MFMA. Targets 4 waves/SIMD.
__global__ __launch_bounds__(512, 4) void pq_main(
    const float* __restrict__ z, const float* __restrict__ cb,
    const float* __restrict__ c2ws, const half8* __restrict__ fragbuf,
    float* __restrict__ out, float* __restrict__ partial)
{
    __shared__ half8    sZfrag[8 * 4 * 64];   // 32 KB: [(rt*4+u)*64 + lane]
    __shared__ unsigned sK1[8 * 128];         // 4 KB
    __shared__ unsigned sK2[8 * 128];         // 4 KB
    __shared__ int      sBest[128];
    __shared__ float    sW[8];

    const int tid = threadIdx.x, bx = blockIdx.x;
    const int m = ((bx & 7) << 3) | ((bx >> 3) & 7);   // XCD m-octet (R11/R15-proven)
    const int chunk = bx >> 6;                          // 0..31
    const int w = tid >> 6, lane = tid & 63;
    const int lh = lane >> 4, l15 = lane & 15;
    const unsigned payBase = 255u - (unsigned)(w * 32 + lh * 4);  // payload = 255 - code

    const float* __restrict__ cbm = cb + (size_t)m * (256 * 64);
    const f4* cb4m = reinterpret_cast<const f4*>(cbm);

    // ---- convert phase: wave w converts row-tile w (R10/R17-validated math) ----
    {
        size_t rh = (size_t)(chunk * 128 + w * 16 + l15);
        const float* zb = z + (rh * 64 + m) * 64 + lh * 8;
        f4 p0 = *reinterpret_cast<const f4*>(zb);
        f4 p1 = *reinterpret_cast<const f4*>(zb + 4);
        f4 p2 = *reinterpret_cast<const f4*>(zb + 32);
        f4 p3 = *reinterpret_cast<const f4*>(zb + 36);
        float v0[8] = {p0.x,p0.y,p0.z,p0.w,p1.x,p1.y,p1.z,p1.w};
        float v1[8] = {p2.x,p2.y,p2.z,p2.w,p3.x,p3.y,p3.z,p3.w};
        half8 h0, l0, h1, l1;
        #pragma unroll
        for (int e = 0; e < 8; ++e) {
            _Float16 a = (_Float16)v0[e];
            h0[e] = a; l0[e] = (_Float16)(v0[e] - (float)a);
            _Float16 b = (_Float16)v1[e];
            h1[e] = b; l1[e] = (_Float16)(v1[e] - (float)b);
        }
        sZfrag[w * 256 +   0 + lane] = h0;
        sZfrag[w * 256 +  64 + lane] = l0;
        sZfrag[w * 256 + 128 + lane] = h1;
        sZfrag[w * 256 + 192 + lane] = l1;
    }

    // ---- A-fragments: 8 coalesced loads (wave's 2 frag-tiles = 32 regs) ----
    const half8* __restrict__ fb = fragbuf + (size_t)m * (16 * 4 * 64);
    half8 ah[2][2], al[2][2];
    #pragma unroll
    for (int t = 0; t < 2; ++t) {
        #pragma unroll
        for (int s = 0; s < 2; ++s) {
            ah[t][s] = fb[((w * 2 + t) * 4 + s * 2 + 0) * 64 + lane];
            al[t][s] = fb[((w * 2 + t) * 4 + s * 2 + 1) * 64 + lane];
        }
    }
    // ---- c2 init per lane: k = w*32 + t*16 + lh*4 + r ----
    const f4* __restrict__ c2t = reinterpret_cast<const f4*>(c2ws + m * 256);
    f32x4 c2i[2];
    #pragma unroll
    for (int t = 0; t < 2; ++t) {
        f4 cv = c2t[(w * 2 + t) * 4 + lh];
        c2i[t][0] = -0.5f*cv.x; c2i[t][1] = -0.5f*cv.y;
        c2i[t][2] = -0.5f*cv.z; c2i[t][3] = -0.5f*cv.w;
    }

    __syncthreads();   // sZfrag complete

    // ---- main: 8 row-tiles x {4 ds_read_b128 + 2x6 MFMA + packed top-2 [R15]} ----
    #pragma unroll 1
    for (int rt = 0; rt < 8; ++rt) {
        const half8* zf = &sZfrag[rt * 256 + lane];
        half8 bh0 = zf[0], bl0 = zf[64], bh1 = zf[128], bl1 = zf[192];
        unsigned K1 = 0u, K2 = 0u;
        #pragma unroll
        for (int t = 0; t < 2; ++t) {
            const unsigned pb = payBase - (unsigned)(t * 16);
            f32x4 acc = c2i[t];
            acc = __builtin_amdgcn_mfma_f32_16x16x32_f16(ah[t][0], bh0, acc, 0, 0, 0);
            acc = __builtin_amdgcn_mfma_f32_16x16x32_f16(ah[t][1], bh1, acc, 0, 0, 0);
            acc = __builtin_amdgcn_mfma_f32_16x16x32_f16(ah[t][0], bl0, acc, 0, 0, 0);
            acc = __builtin_amdgcn_mfma_f32_16x16x32_f16(ah[t][1], bl1, acc, 0, 0, 0);
            acc = __builtin_amdgcn_mfma_f32_16x16x32_f16(al[t][0], bh0, acc, 0, 0, 0);
            acc = __builtin_amdgcn_mfma_f32_16x16x32_f16(al[t][1], bh1, acc, 0, 0, 0);
            unsigned kk0 = (f2mono(acc[0]) & 0xFFFFFF00u) | (pb - 0u);
            unsigned kk1 = (f2mono(acc[1]) & 0xFFFFFF00u) | (pb - 1u);
            unsigned kk2 = (f2mono(acc[2]) & 0xFFFFFF00u) | (pb - 2u);
            unsigned kk3 = (f2mono(acc[3]) & 0xFFFFFF00u) | (pb - 3u);
            unsigned a  = umax(kk0, kk1), b2 = umin(kk0, kk1);
            unsigned c  = umax(kk2, kk3), d  = umin(kk2, kk3);
            unsigned t1 = umax(a, c);
            unsigned t2 = umax(umin(a, c), umax(b2, d));
            K2 = umax(umax(K2, t2), umin(K1, t1));
            K1 = umax(K1, t1);
        }
        #pragma unroll
        for (int off = 16; off <= 32; off <<= 1) {   // merge 4 lane-groups per row
            unsigned o1 = (unsigned)__shfl_xor((int)K1, off, 64);
            unsigned o2 = (unsigned)__shfl_xor((int)K2, off, 64);
            K2 = umax(umax(K2, o2), umin(K1, o1));
            K1 = umax(K1, o1);
        }
        if (lane < 16) {
            sK1[w * 128 + rt * 16 + lane] = K1;
            sK2[w * 128 + rt * 16 + lane] = K2;
        }
    }
    __syncthreads();

    // ---- per-row merge across 8 waves (packed umax tree) [R15 math] ----
    if (tid < 128) {
        unsigned G1 = 0u, G2 = 0u;
        #pragma unroll
        for (int w2 = 0; w2 < 8; ++w2) {
            unsigned k1w = sK1[w2 * 128 + tid];
            unsigned k2w = sK2[w2 * 128 + tid];
            G2 = umax(umax(G2, k2w), umin(G1, k1w));
            G1 = umax(G1, k1w);
        }
        float s1 = mono2f(G1 & 0xFFFFFF00u);
        float s2 = mono2f(G2 & 0xFFFFFF00u);
        sBest[tid] = (s1 - s2 < EPS2) ? -1 : (int)(255u - (G1 & 0xFFu));
    }
    __syncthreads();

    // ---- rescue (rare): exact fp32, z from global (R4/R10-validated math) ----
    for (int row = w; row < 128; row += 8) {
        if (sBest[row] >= 0) continue;            // wave-uniform
        size_t rg = (size_t)(chunk * 128 + row);
        const f4* zr4 = reinterpret_cast<const f4*>(z + (rg * 64 + m) * 64);
        float bs = -1e30f; int bk = 0;
        #pragma unroll 1
        for (int j = 0; j < 4; ++j) {
            int k = j * 64 + lane;
            float s = -0.5f * c2ws[m * 256 + k];
            #pragma unroll
            for (int d4 = 0; d4 < 16; ++d4) {
                f4 cvv = cb4m[k * 16 + d4];
                f4 zz  = zr4[d4];
                s = fmaf(zz.x, cvv.x, s); s = fmaf(zz.y, cvv.y, s);
                s = fmaf(zz.z, cvv.z, s); s = fmaf(zz.w, cvv.w, s);
            }
            if (s > bs) { bs = s; bk = k; }
        }
        #pragma unroll
        for (int off = 1; off < 64; off <<= 1) {
            float ov = __shfl_xor(bs, off, 64);
            int   ok = __shfl_xor(bk, off, 64);
            if (ov > bs || (ov == bs && ok < bk)) { bs = ov; bk = ok; }
        }
        if (lane == 0) sBest[row] = bk;
    }
    __syncthreads();

    // ---- outputs: 64 B contiguous per lane (4-lane clusters fill 256 B lines);
    //      z reconstructed hi+lo from sZfrag (R10/R16-validated) ----
    float lsum = 0.f;
    {
        int row = tid >> 2, q = tid & 3;
        int k = sBest[row];
        int rt2 = row >> 4, rr = row & 15;
        int uh = (q >= 2) ? 2 : 0;
        int lh0 = (q & 1) * 2;
        half8 hi0 = sZfrag[(rt2 * 4 + uh)     * 64 + lh0 * 16 + 16 + rr - 16]; // lh0*16+rr
        half8 hi1 = sZfrag[(rt2 * 4 + uh)     * 64 + (lh0 + 1) * 16 + rr];
        half8 lo0 = sZfrag[(rt2 * 4 + uh + 1) * 64 + lh0 * 16 + rr];
        half8 lo1 = sZfrag[(rt2 * 4 + uh + 1) * 64 + (lh0 + 1) * 16 + rr];
        size_t b = (size_t)(chunk * 128 + row);
        const f4* q4 = cb4m + (size_t)k * 16 + q * 4;
        f4*       o4 = reinterpret_cast<f4*>(out + (b * 64 + m) * 64) + q * 4;
        float l0s = 0.f, l1s = 0.f;
        #pragma unroll
        for (int c = 0; c < 2; ++c) {        // two f4 pairs: dims q*16.. (hi0/lo0 then hi1/lo1)
            f4 qa = q4[c * 2], qb = q4[c * 2 + 1];
            const half8& hh = c ? hi1 : hi0;
            const half8& ll = c ? lo1 : lo0;
            float zr0 = (float)hh[0] + (float)ll[0], zr1 = (float)hh[1] + (float)ll[1];
            float zr2 = (float)hh[2] + (float)ll[2], zr3 = (float)hh[3] + (float)ll[3];
            float zr4 = (float)hh[4] + (float)ll[4], zr5 = (float)hh[5] + (float)ll[5];
            float zr6 = (float)hh[6] + (float)ll[6], zr7 = (float)hh[7] + (float)ll[7];
            o4[c * 2]     = qa;
            o4[c * 2 + 1] = qb;
            float d0 = qa.x - zr0, d1 = qa.y - zr1, d2 = qa.z - zr2, d3 = qa.w - zr3;
            float d4 = qb.x - zr4, d5 = qb.y - zr5, d6 = qb.z - zr6, d7 = qb.w - zr7;
            l0s = fmaf(d0, d0, l0s); l1s = fmaf(d1, d1, l1s);
            l0s = fmaf(d2, d2, l0s); l1s = fmaf(d3, d3, l1s);
            l0s = fmaf(d4, d4, l0s); l1s = fmaf(d5, d5, l1s);
            l0s = fmaf(d6, d6, l0s); l1s = fmaf(d7, d7, l1s);
        }
        lsum = l0s + l1s;
    }
    if (tid < 128)
        out[IDX_BASE + (size_t)(chunk * 128 + tid) * 64 + m] = (float)sBest[tid];
    #pragma unroll
    for (int off = 1; off < 64; off <<= 1) lsum += __shfl_xor(lsum, off, 64);
    if (lane == 0) sW[w] = lsum;
    __syncthreads();
    if (tid == 0) {
        float t = 0.f;
        #pragma unroll
        for (int i = 0; i < 8; ++i) t += sW[i];
        partial[bx] = t;
    }
}

// ---- deterministic final reduction of 2048 block partials -> q_loss ----
__global__ __launch_bounds__(256) void pq_loss(const float* __restrict__ partial,
                                               float* __restrict__ out)
{
    __shared__ float sW[4];
    float s = 0.f;
    #pragma unroll
    for (int i = 0; i < 8; ++i) s += partial[threadIdx.x + i * 256];
    #pragma unroll
    for (int off = 1; off < 64; off <<= 1) s += __shfl_xor(s, off, 64);
    if ((threadIdx.x & 63) == 0) sW[threadIdx.x >> 6] = s;
    __syncthreads();
    if (threadIdx.x == 0)
        out[LOSS_IDX] = ((sW[0] + sW[1]) + (sW[2] + sW[3])) * (1.25f / 16777216.0f);
}

extern "C" void kernel_launch(void* const* d_in, const int* in_sizes, int n_in,
                              void* d_out, int out_size, void* d_ws, size_t ws_size,
                              hipStream_t stream) {
    const float* zp  = (const float*)d_in[0];
    const float* cbp = (const float*)d_in[1];
    float* outp = (float*)d_out;
    float* c2ws = (float*)d_ws;                        // 16384 floats (64 KB)
    half8* frag = (half8*)((float*)d_ws + 16384);      // 4 MB
    float* part = (float*)d_ws + 16384 + 1048576;      // 2048 floats

    pq_frag<<<dim3(256),  dim3(256), 0, stream>>>(cbp, frag, c2ws);
    pq_main<<<dim3(2048), dim3(512), 0, stream>>>(zp, cbp, c2ws, frag, outp, part);
    pq_loss<<<dim3(1),    dim3(256), 0, stream>>>(part, outp);
}